// Round 11
// baseline (553.593 us; speedup 1.0000x reference)
//
#include <hip/hip_runtime.h>
#include <math.h>

typedef __attribute__((ext_vector_type(4))) float f32x4;
typedef __attribute__((ext_vector_type(16))) float f32x16;
typedef __attribute__((ext_vector_type(8))) short s16x8;
typedef __attribute__((ext_vector_type(8))) unsigned short u16x8;
typedef __attribute__((ext_vector_type(4))) unsigned short u16x4;

#define NB 32
#define NN 1000
#define NT 24
#define NP 1024
#define TCN 768

#define GLOAD16(g, l) __builtin_amdgcn_global_load_lds( \
    (const __attribute__((address_space(1))) unsigned int*)(g), \
    (__attribute__((address_space(3))) unsigned int*)(l), 16, 0, 0)

__device__ __forceinline__ unsigned short f2bf(float f){
  union { float fv; unsigned int u; } v; v.fv = f;
  unsigned int r = v.u + 0x7FFFu + ((v.u >> 16) & 1u);
  return (unsigned short)(r >> 16);
}

// ---------------- K0a: cheb[3][1000][1000] f32 -> cbT[3][1024][1024] bf16 (zero pad) ----
__global__ void k0_cheb(const float* __restrict__ cheb, unsigned short* __restrict__ cbT){
  int idx = blockIdx.x * 256 + threadIdx.x;      // 3*1024*1024/4 threads
  int base = idx << 2;
  int m = base & (NP - 1);
  int r = base >> 10;
  int n = r & (NP - 1);
  int k = r >> 10;
  u16x4 o = (u16x4){0,0,0,0};
  if (n < NN && m < NN){
    if (m + 3 < NN){
      f32x4 v = *(const f32x4*)(cheb + ((size_t)k*NN + n)*NN + m);
      o[0] = f2bf(v[0]); o[1] = f2bf(v[1]); o[2] = f2bf(v[2]); o[3] = f2bf(v[3]);
    } else {
      #pragma unroll
      for (int i = 0; i < 4; ++i)
        if (m + i < NN) o[i] = f2bf(cheb[((size_t)k*NN + n)*NN + m + i]);
    }
  }
  *(u16x4*)(cbT + base) = o;
}

// ---------------- K0b: x -> xbT[b][t*32+c][1024 m] bf16 ; xt2[b][m][t*32+c] bf16 --------
__global__ __launch_bounds__(256) void k0_x(const float* __restrict__ x,
                     unsigned short* __restrict__ xbT, unsigned short* __restrict__ xt2){
  __shared__ unsigned short tile[64*770];        // pad 770: transpose reads conflict-free
  const int b  = blockIdx.x >> 4;
  const int m0 = (blockIdx.x & 15) << 6;
  const int tid = threadIdx.x;
  for (int i = tid; i < 64*192; i += 256){
    int mi = i / 192, c4 = (i - mi*192) << 2;
    f32x4 v = (f32x4){0.f,0.f,0.f,0.f};
    if (m0 + mi < NN) v = *(const f32x4*)(x + (size_t)(b*NN + m0 + mi)*768 + c4);
    unsigned short* tp = tile + mi*770 + c4;
    tp[0] = f2bf(v[0]); tp[1] = f2bf(v[1]); tp[2] = f2bf(v[2]); tp[3] = f2bf(v[3]);
  }
  __syncthreads();
  {
    const int seg = tid & 7, r0 = tid >> 3;
    for (int rr = 0; rr < 768; rr += 32){
      int r = rr + r0;
      int t = r >> 5, c = r & 31, ct = c*24 + t;
      u16x8 v;
      #pragma unroll
      for (int e = 0; e < 8; ++e) v[e] = tile[(seg*8 + e)*770 + ct];
      *(u16x8*)(xbT + ((size_t)b*TCN + r)*NP + m0 + seg*8) = v;
    }
  }
  if (m0 < NN){
    int rows = NN - m0; if (rows > 64) rows = 64;
    for (int i = tid; i < rows*96; i += 256){
      int mi = i / 96, s = i - mi*96;
      u16x8 v;
      #pragma unroll
      for (int e = 0; e < 8; ++e){
        int r = s*8 + e; int t = r >> 5, c = r & 31;
        v[e] = tile[mi*770 + c*24 + t];
      }
      *(u16x8*)(xt2 + (size_t)(b*NN + m0 + mi)*TCN + s*8) = v;
    }
  }
}

// ---------------- K0c: weights -> f-major bf16 ------------------------------------------
__global__ void k0_w(const float* __restrict__ Theta, const float* __restrict__ tw,
                     const float* __restrict__ rw,
                     unsigned short* __restrict__ ThT, unsigned short* __restrict__ WtT,
                     unsigned short* __restrict__ rwT){
  int i = blockIdx.x * 256 + threadIdx.x;
  if (i < 64*96){                       // ThT[f][kc] = Theta[k][c][f]
    int f = i / 96, kc = i - f*96;
    ThT[i] = f2bf(Theta[kc*64 + f]);
  }
  if (i < 64*192){                      // WtT[f][dt*64+fi] = tw[f][fi][0][dt]
    int f = i / 192, kk = i - f*192;
    int dt = kk >> 6, fi = kk & 63;
    WtT[i] = f2bf(tw[(f*64 + fi)*3 + dt]);
  }
  if (i < 64*32){                       // rwT[f][c] = rw[f][c][0][0]
    rwT[i] = f2bf(rw[i]);
  }
}

// ---------------- K1: fused cheb-GEMM (3k) + Theta-GEMM + relu -> spatial ----------------
// 256 threads / 4 waves (2wr x 2wc), block tile 64n x 128tc, BK=32, 32x32x16 MFMA.
// A (cbT, L2-resident 6.3MB): register-direct, prefetched 1 step ahead (named regs).
// B (xbT, HBM): global_load_lds into 3 x 8KB buffers, counted vmcnt(2) so B(s+2) stays
// in flight across the barrier (T3+T4 with cheap buffers; LDS 24KB caps nothing).
// LDS/step: 60KB -> 24KB; matrix pipe becomes the binder.
__global__ __launch_bounds__(256, 2) void k1_cheb_theta(
    const unsigned short* __restrict__ cbT,
    const unsigned short* __restrict__ xbT,
    const unsigned short* __restrict__ ThT,
    unsigned short* __restrict__ spa)
{
  __shared__ __align__(16) unsigned short smem[12288];  // 24KB: 3 x B[128][32]; epi yl 13.3KB

  int pB = blockIdx.x;
  int lb = (pB & 7) * 384 + (pB >> 3);     // bijective XCD-chunked swizzle (3072 = 8*384)
  const int tcb = lb % 6; lb /= 6;         // 6 consecutive blocks share the A-panel
  const int nt  = lb & 15;
  const int b   = lb >> 4;

  const int tid  = threadIdx.x;
  const int wid  = tid >> 6;
  const int lane = tid & 63;
  const int l31  = lane & 31;
  const int h    = lane >> 5;
  const int wr   = wid >> 1;    // n-half (32 rows)
  const int wc   = wid & 1;     // tc-half (64 cols)

  // B staging (global_load_lds, source chunk swizzled s(row) = (row>>1)&3)
  const int rl4b = lane >> 2;
  const int swzb = (((lane & 3) ^ ((rl4b >> 1) & 3)) << 3);
  const unsigned short* baseB = xbT + ((size_t)b*TCN + tcb*128 + rl4b)*NP + swzb;
  char* smc = (char*)smem;
  auto stageB = [&](int step, int buf){
    const int so = step << 5;
    const int bo = buf * 8192;                  // bytes
    #pragma unroll
    for (int q = 0; q < 2; ++q){
      const int g = wid*2 + q;                  // 8 x 1KB: rows g*16..g*16+15
      GLOAD16(baseB + (size_t)g*16*NP + so, smc + bo + g*1024);
    }
  };

  // A register-direct base: lane l31 reads row (nt*64 + wr*32 + l31), 16B at k-col h*8
  const unsigned short* gA = cbT + (size_t)(nt*64 + wr*32 + l31)*NP + h*8;

  // B read-side swizzled chunk offsets
  const int s_rd = (l31 >> 1) & 3;
  const int ch0 = ((h ^ s_rd) << 3);
  const int ch1 = (((2 + h) ^ s_rd) << 3);
  const int rB0 = wc*64 + l31;

  f32x16 acc[3][2];
  #pragma unroll
  for (int k = 0; k < 3; ++k)
    #pragma unroll
    for (int j = 0; j < 2; ++j)
      #pragma unroll
      for (int r = 0; r < 16; ++r) acc[k][j][r] = 0.f;

  // prologue: B(0), B(1) staged; A(0) in regs; full drain once
  stageB(0, 0);
  stageB(1, 1);
  s16x8 cA00 = *(const s16x8*)(gA);
  s16x8 cA01 = *(const s16x8*)(gA + 16);
  s16x8 cA10 = *(const s16x8*)(gA + (size_t)NP*NP);
  s16x8 cA11 = *(const s16x8*)(gA + (size_t)NP*NP + 16);
  s16x8 cA20 = *(const s16x8*)(gA + (size_t)2*NP*NP);
  s16x8 cA21 = *(const s16x8*)(gA + (size_t)2*NP*NP + 16);
  asm volatile("s_waitcnt vmcnt(0)" ::: "memory");
  __builtin_amdgcn_s_barrier();

  int cur = 0, pre = 2;
  for (int step = 0; step < 32; ++step){
    s16x8 nA00, nA01, nA10, nA11, nA20, nA21;
    if (step < 31){                             // A(s+1) issued BEFORE B(s+2) stage
      const int so = (step + 1) << 5;
      nA00 = *(const s16x8*)(gA + so);
      nA01 = *(const s16x8*)(gA + so + 16);
      nA10 = *(const s16x8*)(gA + (size_t)NP*NP + so);
      nA11 = *(const s16x8*)(gA + (size_t)NP*NP + so + 16);
      nA20 = *(const s16x8*)(gA + (size_t)2*NP*NP + so);
      nA21 = *(const s16x8*)(gA + (size_t)2*NP*NP + so + 16);
    }
    if (step < 30) stageB(step + 2, pre);

    const unsigned short* sb = smem + cur*4096;
    {   // ks = 0
      s16x8 bf0 = *(const s16x8*)(sb + rB0*32 + ch0);
      s16x8 bf1 = *(const s16x8*)(sb + (rB0 + 32)*32 + ch0);
      acc[0][0] = __builtin_amdgcn_mfma_f32_32x32x16_bf16(cA00, bf0, acc[0][0], 0, 0, 0);
      acc[0][1] = __builtin_amdgcn_mfma_f32_32x32x16_bf16(cA00, bf1, acc[0][1], 0, 0, 0);
      acc[1][0] = __builtin_amdgcn_mfma_f32_32x32x16_bf16(cA10, bf0, acc[1][0], 0, 0, 0);
      acc[1][1] = __builtin_amdgcn_mfma_f32_32x32x16_bf16(cA10, bf1, acc[1][1], 0, 0, 0);
      acc[2][0] = __builtin_amdgcn_mfma_f32_32x32x16_bf16(cA20, bf0, acc[2][0], 0, 0, 0);
      acc[2][1] = __builtin_amdgcn_mfma_f32_32x32x16_bf16(cA20, bf1, acc[2][1], 0, 0, 0);
    }
    {   // ks = 1
      s16x8 bf0 = *(const s16x8*)(sb + rB0*32 + ch1);
      s16x8 bf1 = *(const s16x8*)(sb + (rB0 + 32)*32 + ch1);
      acc[0][0] = __builtin_amdgcn_mfma_f32_32x32x16_bf16(cA01, bf0, acc[0][0], 0, 0, 0);
      acc[0][1] = __builtin_amdgcn_mfma_f32_32x32x16_bf16(cA01, bf1, acc[0][1], 0, 0, 0);
      acc[1][0] = __builtin_amdgcn_mfma_f32_32x32x16_bf16(cA11, bf0, acc[1][0], 0, 0, 0);
      acc[1][1] = __builtin_amdgcn_mfma_f32_32x32x16_bf16(cA11, bf1, acc[1][1], 0, 0, 0);
      acc[2][0] = __builtin_amdgcn_mfma_f32_32x32x16_bf16(cA21, bf0, acc[2][0], 0, 0, 0);
      acc[2][1] = __builtin_amdgcn_mfma_f32_32x32x16_bf16(cA21, bf1, acc[2][1], 0, 0, 0);
    }
    cA00 = nA00; cA01 = nA01; cA10 = nA10; cA11 = nA11; cA20 = nA20; cA21 = nA21;

    if (step < 30)       asm volatile("s_waitcnt vmcnt(2)" ::: "memory");  // B(s+2) stays in flight
    else if (step == 30) asm volatile("s_waitcnt vmcnt(0)" ::: "memory");  // tail drain
    __builtin_amdgcn_s_barrier();
    cur = (cur == 2) ? 0 : cur + 1;
    pre = (pre == 2) ? 0 : pre + 1;
  }

  // ---- epilogue: 4 t-phases; y -> LDS bf16 (chunk-XOR) -> Theta MFMA (32x32) -> relu ----
  s16x8 b2[3][2];
  const int fE = wc*32 + l31;
  #pragma unroll
  for (int ch = 0; ch < 3; ++ch)
    #pragma unroll
    for (int ks = 0; ks < 2; ++ks)
      b2[ch][ks] = *(const s16x8*)(ThT + fE*96 + ch*32 + ks*16 + h*8);

  unsigned short* yl = smem;                 // [64 n][104 kc], chunk-XOR swizzled (13.3KB)
  const int rowE = wr*32 + l31;
  #pragma unroll
  for (int p = 0; p < 4; ++p){
    __syncthreads();
    if (wc == (p >> 1)){
      const int jj = p & 1;
      #pragma unroll
      for (int k = 0; k < 3; ++k)
        #pragma unroll
        for (int r = 0; r < 16; ++r){
          const int nl = wr*32 + (r & 3) + ((r >> 2) << 3) + (h << 2);
          const int kc = k*32 + l31;
          const int q  = kc >> 3;
          yl[nl*104 + (((q ^ (nl & 3)) << 3) | (kc & 7))] = f2bf(acc[k][jj][r]);
        }
    }
    __syncthreads();
    f32x16 a2c;
    #pragma unroll
    for (int r = 0; r < 16; ++r) a2c[r] = 0.f;
    #pragma unroll
    for (int ch = 0; ch < 3; ++ch)
      #pragma unroll
      for (int ks = 0; ks < 2; ++ks){
        const int q = ch*4 + ks*2 + h;
        s16x8 a2 = *(const s16x8*)(yl + rowE*104 + ((q ^ (rowE & 3)) << 3));
        a2c = __builtin_amdgcn_mfma_f32_32x32x16_bf16(a2, b2[ch][ks], a2c, 0, 0, 0);
      }
    const int t = tcb*4 + p;
    #pragma unroll
    for (int r = 0; r < 16; ++r){
      const int nl = wr*32 + (r & 3) + ((r >> 2) << 3) + (h << 2);
      const int n  = nt*64 + nl;
      if (n < NN)
        spa[((size_t)(b*NN + n)*NT + t)*64 + fE] = f2bf(fmaxf(a2c[r], 0.f));
    }
  }
}

// ---------------- K2 v3: LDS-staged time-conv + residual + gating -> out f32 ------------
__global__ __launch_bounds__(256, 2) void k2_out(
    const unsigned short* __restrict__ spa, const unsigned short* __restrict__ xt2,
    const unsigned short* __restrict__ WtT, const unsigned short* __restrict__ rwT,
    const float* __restrict__ tb, const float* __restrict__ rb,
    float* __restrict__ out)
{
  __shared__ __align__(16) unsigned short sst[36864];   // 72KB = spa 48KB + xt2 24KB
  const unsigned short* spa_s = sst;
  const unsigned short* xt2_s = sst + 24576;

  const int c0   = blockIdx.x * 16;
  const int tid  = threadIdx.x;
  const int w    = tid >> 6;
  const int lane = tid & 63;
  const int l31  = lane & 31;
  const int h    = lane >> 5;
  char* smc = (char*)sst;

  // ---- stage: fully coalesced contiguous ranges, source chunk pre-swizzled ----
  const unsigned short* gs = spa + (size_t)c0 * 1536;   // 16 cells x 24t x 64f
  const unsigned short* gx = xt2 + (size_t)c0 * 768;    // 16 cells x 768
  #pragma unroll
  for (int it = 0; it < 12; ++it){                      // spa: rows of 128B, s8(row)=row&7
    const int row = it*32 + (tid >> 3);
    const int sc  = (tid & 7) ^ (row & 7);
    GLOAD16(gs + (size_t)row*64 + sc*8, smc + it*4096 + w*1024);
  }
  #pragma unroll
  for (int it = 0; it < 6; ++it){                       // xt2: rows of 64B, s4=(row>>1)&3
    const int row = it*64 + (tid >> 2);
    const int sc  = (tid & 3) ^ ((row >> 1) & 3);
    GLOAD16(gx + (size_t)row*32 + sc*8, smc + 49152 + it*4096 + w*1024);
  }
  __syncthreads();

  const float tb0v = tb[l31], tb1v = tb[32 + l31];
  const float rb0v = rb[l31], rb1v = rb[32 + l31];

  #pragma unroll
  for (int g = 0; g < 3; ++g){
    const int rbase = w*96 + g*32;
    const int r = rbase + l31;                 // 0..383
    const int cell = r / 24;
    const int t = r - cell*24;

    f32x16 a0, a1, rs0, rs1;
    #pragma unroll
    for (int e = 0; e < 16; ++e){ a0[e]=0.f; a1[e]=0.f; rs0[e]=0.f; rs1[e]=0.f; }

    #pragma unroll
    for (int s = 0; s < 12; ++s){              // time-conv K-slices: dt=s>>2, fb=s&3
      const int dt = s >> 2;
      const int tv = t + dt - 1;
      int ar = r + dt - 1;
      ar = ar < 0 ? 0 : (ar > 383 ? 383 : ar);
      const int cfi = ((s & 3) << 1) + h;
      s16x8 a = *(const s16x8*)(spa_s + (size_t)ar*64 + ((cfi ^ (ar & 7)) << 3));
      if (!((unsigned)tv < 24u)) a = (s16x8){0,0,0,0,0,0,0,0};
      s16x8 b0 = *(const s16x8*)(WtT + (size_t)l31*192 + s*16 + h*8);
      s16x8 b1 = *(const s16x8*)(WtT + (size_t)(32 + l31)*192 + s*16 + h*8);
      a0 = __builtin_amdgcn_mfma_f32_32x32x16_bf16(a, b0, a0, 0, 0, 0);
      a1 = __builtin_amdgcn_mfma_f32_32x32x16_bf16(a, b1, a1, 0, 0, 0);
    }
    #pragma unroll
    for (int s = 0; s < 2; ++s){               // residual K=32
      const int cres = (s << 1) + h;
      s16x8 a = *(const s16x8*)(xt2_s + (size_t)r*32 + ((cres ^ ((r >> 1) & 3)) << 3));
      s16x8 b0 = *(const s16x8*)(rwT + (size_t)l31*32 + s*16 + h*8);
      s16x8 b1 = *(const s16x8*)(rwT + (size_t)(32 + l31)*32 + s*16 + h*8);
      rs0 = __builtin_amdgcn_mfma_f32_32x32x16_bf16(a, b0, rs0, 0, 0, 0);
      rs1 = __builtin_amdgcn_mfma_f32_32x32x16_bf16(a, b1, rs1, 0, 0, 0);
    }

    // gate + store: quad q covers rows rbase + q*8 + 4h + 0..3 (t stays in one cell)
    #pragma unroll
    for (int q = 0; q < 4; ++q){
      const int rq = rbase + q*8 + 4*h;
      const int cq = rq / 24;
      const int tq = rq - cq*24;
      f32x4 v0, v1;
      #pragma unroll
      for (int e = 0; e < 4; ++e){
        float z0 = a0[q*4 + e] + tb0v;
        float e0 = __expf(-z0);
        v0[e] = rs0[q*4 + e] + rb0v + (1.f - e0) * __builtin_amdgcn_rcpf(1.f + e0*e0);
        float z1 = a1[q*4 + e] + tb1v;
        float e1 = __expf(-z1);
        v1[e] = rs1[q*4 + e] + rb1v + (1.f - e1) * __builtin_amdgcn_rcpf(1.f + e1*e1);
      }
      *(f32x4*)(out + ((size_t)(c0 + cq)*64 + l31)*24 + tq)      = v0;
      *(f32x4*)(out + ((size_t)(c0 + cq)*64 + 32 + l31)*24 + tq) = v1;
    }
  }
}

// ---------------- launch -----------------------------------------------------------------
extern "C" void kernel_launch(void* const* d_in, const int* in_sizes, int n_in,
                              void* d_out, int out_size, void* d_ws, size_t ws_size,
                              hipStream_t stream) {
  const float* x     = (const float*)d_in[0];
  const float* cheb  = (const float*)d_in[1];
  const float* Theta = (const float*)d_in[2];
  const float* tw    = (const float*)d_in[3];
  const float* tb    = (const float*)d_in[4];
  const float* rw    = (const float*)d_in[5];
  const float* rb    = (const float*)d_in[6];
  float* out = (float*)d_out;

  char* ws = (char*)d_ws;
  size_t off = 0;
  auto alloc = [&](size_t bytes) -> void* {
    void* p = ws + off;
    off += (bytes + 255) & ~(size_t)255;
    return p;
  };
  unsigned short* cbT = (unsigned short*)alloc((size_t)3*NP*NP*2);        //  6.3 MB
  unsigned short* xbT = (unsigned short*)alloc((size_t)NB*TCN*NP*2);      // 50.3 MB
  unsigned short* xt2 = (unsigned short*)alloc((size_t)NB*NN*TCN*2);      // 49.2 MB
  unsigned short* spa = (unsigned short*)alloc((size_t)NB*NN*NT*64*2);    // 98.3 MB
  unsigned short* ThT = (unsigned short*)alloc((size_t)64*96*2);
  unsigned short* WtT = (unsigned short*)alloc((size_t)64*192*2);
  unsigned short* rwT = (unsigned short*)alloc((size_t)64*32*2);

  hipLaunchKernelGGL(k0_cheb, dim3(3072), dim3(256), 0, stream, cheb, cbT);
  hipLaunchKernelGGL(k0_x,    dim3(512),  dim3(256), 0, stream, x, xbT, xt2);
  hipLaunchKernelGGL(k0_w,    dim3(48),   dim3(256), 0, stream, Theta, tw, rw, ThT, WtT, rwT);
  hipLaunchKernelGGL(k1_cheb_theta, dim3(32*16*6), dim3(256), 0, stream, cbT, xbT, ThT, spa);
  hipLaunchKernelGGL(k2_out,  dim3(2000), dim3(256), 0, stream, spa, xt2, WtT, rwT, tb, rb, out);
}

// Round 12
// 427.776 us; speedup vs baseline: 1.2941x; 1.2941x over previous
//
#include <hip/hip_runtime.h>
#include <math.h>

typedef __attribute__((ext_vector_type(4))) float f32x4;
typedef __attribute__((ext_vector_type(16))) float f32x16;
typedef __attribute__((ext_vector_type(8))) short s16x8;
typedef __attribute__((ext_vector_type(8))) unsigned short u16x8;
typedef __attribute__((ext_vector_type(4))) unsigned short u16x4;

#define NB 32
#define NN 1000
#define NT 24
#define NP 1024
#define TCN 768

#define GLOAD16(g, l) __builtin_amdgcn_global_load_lds( \
    (const __attribute__((address_space(1))) unsigned int*)(g), \
    (__attribute__((address_space(3))) unsigned int*)(l), 16, 0, 0)

__device__ __forceinline__ unsigned short f2bf(float f){
  union { float fv; unsigned int u; } v; v.fv = f;
  unsigned int r = v.u + 0x7FFFu + ((v.u >> 16) & 1u);
  return (unsigned short)(r >> 16);
}

// ---------------- K0a: cheb[3][1000][1000] f32 -> cbT[3][1024][1024] bf16 (zero pad) ----
__global__ void k0_cheb(const float* __restrict__ cheb, unsigned short* __restrict__ cbT){
  int idx = blockIdx.x * 256 + threadIdx.x;      // 3*1024*1024/4 threads
  int base = idx << 2;
  int m = base & (NP - 1);
  int r = base >> 10;
  int n = r & (NP - 1);
  int k = r >> 10;
  u16x4 o = (u16x4){0,0,0,0};
  if (n < NN && m < NN){
    if (m + 3 < NN){
      f32x4 v = *(const f32x4*)(cheb + ((size_t)k*NN + n)*NN + m);
      o[0] = f2bf(v[0]); o[1] = f2bf(v[1]); o[2] = f2bf(v[2]); o[3] = f2bf(v[3]);
    } else {
      #pragma unroll
      for (int i = 0; i < 4; ++i)
        if (m + i < NN) o[i] = f2bf(cheb[((size_t)k*NN + n)*NN + m + i]);
    }
  }
  *(u16x4*)(cbT + base) = o;
}

// ---------------- K0b: x -> xbT[b][t*32+c][1024 m] bf16 ; xt2[b][m][t*32+c] bf16 --------
__global__ __launch_bounds__(256) void k0_x(const float* __restrict__ x,
                     unsigned short* __restrict__ xbT, unsigned short* __restrict__ xt2){
  __shared__ unsigned short tile[64*770];        // pad 770: transpose reads conflict-free
  const int b  = blockIdx.x >> 4;
  const int m0 = (blockIdx.x & 15) << 6;
  const int tid = threadIdx.x;
  for (int i = tid; i < 64*192; i += 256){
    int mi = i / 192, c4 = (i - mi*192) << 2;
    f32x4 v = (f32x4){0.f,0.f,0.f,0.f};
    if (m0 + mi < NN) v = *(const f32x4*)(x + (size_t)(b*NN + m0 + mi)*768 + c4);
    unsigned short* tp = tile + mi*770 + c4;
    tp[0] = f2bf(v[0]); tp[1] = f2bf(v[1]); tp[2] = f2bf(v[2]); tp[3] = f2bf(v[3]);
  }
  __syncthreads();
  {
    const int seg = tid & 7, r0 = tid >> 3;
    for (int rr = 0; rr < 768; rr += 32){
      int r = rr + r0;
      int t = r >> 5, c = r & 31, ct = c*24 + t;
      u16x8 v;
      #pragma unroll
      for (int e = 0; e < 8; ++e) v[e] = tile[(seg*8 + e)*770 + ct];
      *(u16x8*)(xbT + ((size_t)b*TCN + r)*NP + m0 + seg*8) = v;
    }
  }
  if (m0 < NN){
    int rows = NN - m0; if (rows > 64) rows = 64;
    for (int i = tid; i < rows*96; i += 256){
      int mi = i / 96, s = i - mi*96;
      u16x8 v;
      #pragma unroll
      for (int e = 0; e < 8; ++e){
        int r = s*8 + e; int t = r >> 5, c = r & 31;
        v[e] = tile[mi*770 + c*24 + t];
      }
      *(u16x8*)(xt2 + (size_t)(b*NN + m0 + mi)*TCN + s*8) = v;
    }
  }
}

// ---------------- K0c: weights -> f-major bf16 ------------------------------------------
__global__ void k0_w(const float* __restrict__ Theta, const float* __restrict__ tw,
                     const float* __restrict__ rw,
                     unsigned short* __restrict__ ThT, unsigned short* __restrict__ WtT,
                     unsigned short* __restrict__ rwT){
  int i = blockIdx.x * 256 + threadIdx.x;
  if (i < 64*96){                       // ThT[f][kc] = Theta[k][c][f]
    int f = i / 96, kc = i - f*96;
    ThT[i] = f2bf(Theta[kc*64 + f]);
  }
  if (i < 64*192){                      // WtT[f][dt*64+fi] = tw[f][fi][0][dt]
    int f = i / 192, kk = i - f*192;
    int dt = kk >> 6, fi = kk & 63;
    WtT[i] = f2bf(tw[(f*64 + fi)*3 + dt]);
  }
  if (i < 64*32){                       // rwT[f][c] = rw[f][c][0][0]
    rwT[i] = f2bf(rw[i]);
  }
}

// ---------------- K1: fused cheb-GEMM (3k) + Theta-GEMM + relu -> spatial ----------------
// 256 threads / 4 waves (2wr x 2wc), block tile 64n x 128tc, BK=32, 32x32x16 MFMA.
// BARRIER-FREE K-loop: each wave stages ITS OWN fragments (A: 32n x 3k, B: 64tc) into a
// private 10KB LDS region, double-buffered (80KB). Correctness by per-wave vmcnt(10)
// only (batch s completed when batch s+1's 10 gloads are the only outstanding VMEM).
// Waves drift freely -> mutual latency hiding; setprio(1) around the MFMA cluster.
// Both-sides swizzle s(row) = (row>>1)&3 (verified conflict-free).
__global__ __launch_bounds__(256, 2) void k1_cheb_theta(
    const unsigned short* __restrict__ cbT,
    const unsigned short* __restrict__ xbT,
    const unsigned short* __restrict__ ThT,
    unsigned short* __restrict__ spa)
{
  __shared__ __align__(16) unsigned short smem[40960];  // 80KB: 2 buf x 4 waves x 5120 el

  int pB = blockIdx.x;
  int lb = (pB & 7) * 384 + (pB >> 3);     // bijective XCD-chunked swizzle (3072 = 8*384)
  const int tcb = lb % 6; lb /= 6;         // 6 consecutive blocks share the A-panel
  const int nt  = lb & 15;
  const int b   = lb >> 4;

  const int tid  = threadIdx.x;
  const int wid  = tid >> 6;
  const int lane = tid & 63;
  const int l31  = lane & 31;
  const int h    = lane >> 5;
  const int wr   = wid >> 1;    // n-half (32 rows)
  const int wc   = wid & 1;     // tc-half (64 cols)

  // wave-private staging: A rows wr*32.., B rows wc*64.. ; source chunk swizzled
  const int rl4 = lane >> 2;
  const int swz = (((lane & 3) ^ ((rl4 >> 1) & 3)) << 3);
  const unsigned short* baseA = cbT + (size_t)(nt*64 + wr*32 + rl4)*NP + swz;
  const unsigned short* baseB = xbT + ((size_t)b*TCN + tcb*128 + wc*64 + rl4)*NP + swz;
  char* smc = (char*)smem;

  auto stage = [&](int step, int buf){       // 10 x 1KB gloads, all wave-private
    const int so = step << 5;
    char* d = smc + buf*40960 + wid*10240;   // [buf][wid] region, bytes
    #pragma unroll
    for (int k = 0; k < 3; ++k)
      #pragma unroll
      for (int rg = 0; rg < 2; ++rg)
        GLOAD16(baseA + (size_t)k*NP*NP + (size_t)rg*16*NP + so, d + k*2048 + rg*1024);
    #pragma unroll
    for (int rg = 0; rg < 4; ++rg)
      GLOAD16(baseB + (size_t)rg*16*NP + so, d + 6144 + rg*1024);
  };

  // read-side swizzled chunk offsets (elements); s(row) = (l31>>1)&3
  const int s_rd = (l31 >> 1) & 3;
  const int ch0 = ((h ^ s_rd) << 3);
  const int ch1 = (((2 + h) ^ s_rd) << 3);

  f32x16 acc[3][2];
  #pragma unroll
  for (int k = 0; k < 3; ++k)
    #pragma unroll
    for (int j = 0; j < 2; ++j)
      #pragma unroll
      for (int r = 0; r < 16; ++r) acc[k][j][r] = 0.f;

  stage(0, 0);

  int cur = 0;
  for (int step = 0; step < 32; ++step){
    if (step < 31){
      stage(step + 1, cur ^ 1);
      asm volatile("s_waitcnt vmcnt(10)" ::: "memory");   // batch(step) landed
    } else {
      asm volatile("s_waitcnt vmcnt(0)" ::: "memory");    // tail drain
    }
    const unsigned short* wb = smem + cur*20480 + wid*5120;  // elements
    {   // ks = 0
      s16x8 af0 = *(const s16x8*)(wb +        l31*32 + ch0);
      s16x8 af1 = *(const s16x8*)(wb + 1024 + l31*32 + ch0);
      s16x8 af2 = *(const s16x8*)(wb + 2048 + l31*32 + ch0);
      s16x8 bf0 = *(const s16x8*)(wb + 3072 + l31*32 + ch0);
      s16x8 bf1 = *(const s16x8*)(wb + 3072 + (32 + l31)*32 + ch0);
      __builtin_amdgcn_s_setprio(1);
      acc[0][0] = __builtin_amdgcn_mfma_f32_32x32x16_bf16(af0, bf0, acc[0][0], 0, 0, 0);
      acc[0][1] = __builtin_amdgcn_mfma_f32_32x32x16_bf16(af0, bf1, acc[0][1], 0, 0, 0);
      acc[1][0] = __builtin_amdgcn_mfma_f32_32x32x16_bf16(af1, bf0, acc[1][0], 0, 0, 0);
      acc[1][1] = __builtin_amdgcn_mfma_f32_32x32x16_bf16(af1, bf1, acc[1][1], 0, 0, 0);
      acc[2][0] = __builtin_amdgcn_mfma_f32_32x32x16_bf16(af2, bf0, acc[2][0], 0, 0, 0);
      acc[2][1] = __builtin_amdgcn_mfma_f32_32x32x16_bf16(af2, bf1, acc[2][1], 0, 0, 0);
      __builtin_amdgcn_s_setprio(0);
    }
    {   // ks = 1
      s16x8 af0 = *(const s16x8*)(wb +        l31*32 + ch1);
      s16x8 af1 = *(const s16x8*)(wb + 1024 + l31*32 + ch1);
      s16x8 af2 = *(const s16x8*)(wb + 2048 + l31*32 + ch1);
      s16x8 bf0 = *(const s16x8*)(wb + 3072 + l31*32 + ch1);
      s16x8 bf1 = *(const s16x8*)(wb + 3072 + (32 + l31)*32 + ch1);
      __builtin_amdgcn_s_setprio(1);
      acc[0][0] = __builtin_amdgcn_mfma_f32_32x32x16_bf16(af0, bf0, acc[0][0], 0, 0, 0);
      acc[0][1] = __builtin_amdgcn_mfma_f32_32x32x16_bf16(af0, bf1, acc[0][1], 0, 0, 0);
      acc[1][0] = __builtin_amdgcn_mfma_f32_32x32x16_bf16(af1, bf0, acc[1][0], 0, 0, 0);
      acc[1][1] = __builtin_amdgcn_mfma_f32_32x32x16_bf16(af1, bf1, acc[1][1], 0, 0, 0);
      acc[2][0] = __builtin_amdgcn_mfma_f32_32x32x16_bf16(af2, bf0, acc[2][0], 0, 0, 0);
      acc[2][1] = __builtin_amdgcn_mfma_f32_32x32x16_bf16(af2, bf1, acc[2][1], 0, 0, 0);
      __builtin_amdgcn_s_setprio(0);
    }
    cur ^= 1;
  }

  __syncthreads();                           // all waves done with private bufs

  // ---- epilogue: 4 t-phases; y -> LDS bf16 (chunk-XOR) -> Theta MFMA (32x32) -> relu ----
  s16x8 b2[3][2];
  const int fE = wc*32 + l31;
  #pragma unroll
  for (int ch = 0; ch < 3; ++ch)
    #pragma unroll
    for (int ks = 0; ks < 2; ++ks)
      b2[ch][ks] = *(const s16x8*)(ThT + fE*96 + ch*32 + ks*16 + h*8);

  unsigned short* yl = smem;                 // [64 n][104 kc], chunk-XOR swizzled (13.3KB)
  const int rowE = wr*32 + l31;
  #pragma unroll
  for (int p = 0; p < 4; ++p){
    __syncthreads();
    if (wc == (p >> 1)){
      const int jj = p & 1;
      #pragma unroll
      for (int k = 0; k < 3; ++k)
        #pragma unroll
        for (int r = 0; r < 16; ++r){
          const int nl = wr*32 + (r & 3) + ((r >> 2) << 3) + (h << 2);
          const int kc = k*32 + l31;
          const int q  = kc >> 3;
          yl[nl*104 + (((q ^ (nl & 3)) << 3) | (kc & 7))] = f2bf(acc[k][jj][r]);
        }
    }
    __syncthreads();
    f32x16 a2c;
    #pragma unroll
    for (int r = 0; r < 16; ++r) a2c[r] = 0.f;
    #pragma unroll
    for (int ch = 0; ch < 3; ++ch)
      #pragma unroll
      for (int ks = 0; ks < 2; ++ks){
        const int q = ch*4 + ks*2 + h;
        s16x8 a2 = *(const s16x8*)(yl + rowE*104 + ((q ^ (rowE & 3)) << 3));
        a2c = __builtin_amdgcn_mfma_f32_32x32x16_bf16(a2, b2[ch][ks], a2c, 0, 0, 0);
      }
    const int t = tcb*4 + p;
    #pragma unroll
    for (int r = 0; r < 16; ++r){
      const int nl = wr*32 + (r & 3) + ((r >> 2) << 3) + (h << 2);
      const int n  = nt*64 + nl;
      if (n < NN)
        spa[((size_t)(b*NN + n)*NT + t)*64 + fE] = f2bf(fmaxf(a2c[r], 0.f));
    }
  }
}

// ---------------- K2 v3: LDS-staged time-conv + residual + gating -> out f32 ------------
__global__ __launch_bounds__(256, 2) void k2_out(
    const unsigned short* __restrict__ spa, const unsigned short* __restrict__ xt2,
    const unsigned short* __restrict__ WtT, const unsigned short* __restrict__ rwT,
    const float* __restrict__ tb, const float* __restrict__ rb,
    float* __restrict__ out)
{
  __shared__ __align__(16) unsigned short sst[36864];   // 72KB = spa 48KB + xt2 24KB
  const unsigned short* spa_s = sst;
  const unsigned short* xt2_s = sst + 24576;

  const int c0   = blockIdx.x * 16;
  const int tid  = threadIdx.x;
  const int w    = tid >> 6;
  const int lane = tid & 63;
  const int l31  = lane & 31;
  const int h    = lane >> 5;
  char* smc = (char*)sst;

  // ---- stage: fully coalesced contiguous ranges, source chunk pre-swizzled ----
  const unsigned short* gs = spa + (size_t)c0 * 1536;   // 16 cells x 24t x 64f
  const unsigned short* gx = xt2 + (size_t)c0 * 768;    // 16 cells x 768
  #pragma unroll
  for (int it = 0; it < 12; ++it){                      // spa: rows of 128B, s8(row)=row&7
    const int row = it*32 + (tid >> 3);
    const int sc  = (tid & 7) ^ (row & 7);
    GLOAD16(gs + (size_t)row*64 + sc*8, smc + it*4096 + w*1024);
  }
  #pragma unroll
  for (int it = 0; it < 6; ++it){                       // xt2: rows of 64B, s4=(row>>1)&3
    const int row = it*64 + (tid >> 2);
    const int sc  = (tid & 3) ^ ((row >> 1) & 3);
    GLOAD16(gx + (size_t)row*32 + sc*8, smc + 49152 + it*4096 + w*1024);
  }
  __syncthreads();

  const float tb0v = tb[l31], tb1v = tb[32 + l31];
  const float rb0v = rb[l31], rb1v = rb[32 + l31];

  #pragma unroll
  for (int g = 0; g < 3; ++g){
    const int rbase = w*96 + g*32;
    const int r = rbase + l31;                 // 0..383
    const int cell = r / 24;
    const int t = r - cell*24;

    f32x16 a0, a1, rs0, rs1;
    #pragma unroll
    for (int e = 0; e < 16; ++e){ a0[e]=0.f; a1[e]=0.f; rs0[e]=0.f; rs1[e]=0.f; }

    #pragma unroll
    for (int s = 0; s < 12; ++s){              // time-conv K-slices: dt=s>>2, fb=s&3
      const int dt = s >> 2;
      const int tv = t + dt - 1;
      int ar = r + dt - 1;
      ar = ar < 0 ? 0 : (ar > 383 ? 383 : ar);
      const int cfi = ((s & 3) << 1) + h;
      s16x8 a = *(const s16x8*)(spa_s + (size_t)ar*64 + ((cfi ^ (ar & 7)) << 3));
      if (!((unsigned)tv < 24u)) a = (s16x8){0,0,0,0,0,0,0,0};
      s16x8 b0 = *(const s16x8*)(WtT + (size_t)l31*192 + s*16 + h*8);
      s16x8 b1 = *(const s16x8*)(WtT + (size_t)(32 + l31)*192 + s*16 + h*8);
      a0 = __builtin_amdgcn_mfma_f32_32x32x16_bf16(a, b0, a0, 0, 0, 0);
      a1 = __builtin_amdgcn_mfma_f32_32x32x16_bf16(a, b1, a1, 0, 0, 0);
    }
    #pragma unroll
    for (int s = 0; s < 2; ++s){               // residual K=32
      const int cres = (s << 1) + h;
      s16x8 a = *(const s16x8*)(xt2_s + (size_t)r*32 + ((cres ^ ((r >> 1) & 3)) << 3));
      s16x8 b0 = *(const s16x8*)(rwT + (size_t)l31*32 + s*16 + h*8);
      s16x8 b1 = *(const s16x8*)(rwT + (size_t)(32 + l31)*32 + s*16 + h*8);
      rs0 = __builtin_amdgcn_mfma_f32_32x32x16_bf16(a, b0, rs0, 0, 0, 0);
      rs1 = __builtin_amdgcn_mfma_f32_32x32x16_bf16(a, b1, rs1, 0, 0, 0);
    }

    // gate + store: quad q covers rows rbase + q*8 + 4h + 0..3 (t stays in one cell)
    #pragma unroll
    for (int q = 0; q < 4; ++q){
      const int rq = rbase + q*8 + 4*h;
      const int cq = rq / 24;
      const int tq = rq - cq*24;
      f32x4 v0, v1;
      #pragma unroll
      for (int e = 0; e < 4; ++e){
        float z0 = a0[q*4 + e] + tb0v;
        float e0 = __expf(-z0);
        v0[e] = rs0[q*4 + e] + rb0v + (1.f - e0) * __builtin_amdgcn_rcpf(1.f + e0*e0);
        float z1 = a1[q*4 + e] + tb1v;
        float e1 = __expf(-z1);
        v1[e] = rs1[q*4 + e] + rb1v + (1.f - e1) * __builtin_amdgcn_rcpf(1.f + e1*e1);
      }
      *(f32x4*)(out + ((size_t)(c0 + cq)*64 + l31)*24 + tq)      = v0;
      *(f32x4*)(out + ((size_t)(c0 + cq)*64 + 32 + l31)*24 + tq) = v1;
    }
  }
}

// ---------------- launch -----------------------------------------------------------------
extern "C" void kernel_launch(void* const* d_in, const int* in_sizes, int n_in,
                              void* d_out, int out_size, void* d_ws, size_t ws_size,
                              hipStream_t stream) {
  const float* x     = (const float*)d_in[0];
  const float* cheb  = (const float*)d_in[1];
  const float* Theta = (const float*)d_in[2];
  const float* tw    = (const float*)d_in[3];
  const float* tb    = (const float*)d_in[4];
  const float* rw    = (const float*)d_in[5];
  const float* rb    = (const float*)d_in[6];
  float* out = (float*)d_out;

  char* ws = (char*)d_ws;
  size_t off = 0;
  auto alloc = [&](size_t bytes) -> void* {
    void* p = ws + off;
    off += (bytes + 255) & ~(size_t)255;
    return p;
  };
  unsigned short* cbT = (unsigned short*)alloc((size_t)3*NP*NP*2);        //  6.3 MB
  unsigned short* xbT = (unsigned short*)alloc((size_t)NB*TCN*NP*2);      // 50.3 MB
  unsigned short* xt2 = (unsigned short*)alloc((size_t)NB*NN*TCN*2);      // 49.2 MB
  unsigned short* spa = (unsigned short*)alloc((size_t)NB*NN*NT*64*2);    // 98.3 MB
  unsigned short* ThT = (unsigned short*)alloc((size_t)64*96*2);
  unsigned short* WtT = (unsigned short*)alloc((size_t)64*192*2);
  unsigned short* rwT = (unsigned short*)alloc((size_t)64*32*2);

  hipLaunchKernelGGL(k0_cheb, dim3(3072), dim3(256), 0, stream, cheb, cbT);
  hipLaunchKernelGGL(k0_x,    dim3(512),  dim3(256), 0, stream, x, xbT, xt2);
  hipLaunchKernelGGL(k0_w,    dim3(48),   dim3(256), 0, stream, Theta, tw, rw, ThT, WtT, rwT);
  hipLaunchKernelGGL(k1_cheb_theta, dim3(32*16*6), dim3(256), 0, stream, cbT, xbT, ThT, spa);
  hipLaunchKernelGGL(k2_out,  dim3(2000), dim3(256), 0, stream, spa, xt2, WtT, rwT, tb, rb, out);
}

// Round 13
// 388.118 us; speedup vs baseline: 1.4264x; 1.1022x over previous
//
#include <hip/hip_runtime.h>
#include <math.h>

typedef __attribute__((ext_vector_type(4))) float f32x4;
typedef __attribute__((ext_vector_type(16))) float f32x16;
typedef __attribute__((ext_vector_type(8))) short s16x8;
typedef __attribute__((ext_vector_type(8))) unsigned short u16x8;
typedef __attribute__((ext_vector_type(4))) unsigned short u16x4;

#define NB 32
#define NN 1000
#define NT 24
#define NP 1024
#define TCN 768

#define GLOAD16(g, l) __builtin_amdgcn_global_load_lds( \
    (const __attribute__((address_space(1))) unsigned int*)(g), \
    (__attribute__((address_space(3))) unsigned int*)(l), 16, 0, 0)

__device__ __forceinline__ unsigned short f2bf(float f){
  union { float fv; unsigned int u; } v; v.fv = f;
  unsigned int r = v.u + 0x7FFFu + ((v.u >> 16) & 1u);
  return (unsigned short)(r >> 16);
}

// ---------------- K0a: cheb[3][1000][1000] f32 -> cbT[3][1024][1024] bf16 (zero pad) ----
__global__ void k0_cheb(const float* __restrict__ cheb, unsigned short* __restrict__ cbT){
  int idx = blockIdx.x * 256 + threadIdx.x;      // 3*1024*1024/4 threads
  int base = idx << 2;
  int m = base & (NP - 1);
  int r = base >> 10;
  int n = r & (NP - 1);
  int k = r >> 10;
  u16x4 o = (u16x4){0,0,0,0};
  if (n < NN && m < NN){
    if (m + 3 < NN){
      f32x4 v = *(const f32x4*)(cheb + ((size_t)k*NN + n)*NN + m);
      o[0] = f2bf(v[0]); o[1] = f2bf(v[1]); o[2] = f2bf(v[2]); o[3] = f2bf(v[3]);
    } else {
      #pragma unroll
      for (int i = 0; i < 4; ++i)
        if (m + i < NN) o[i] = f2bf(cheb[((size_t)k*NN + n)*NN + m + i]);
    }
  }
  *(u16x4*)(cbT + base) = o;
}

// ---------------- K0b: x -> xbT[b][t*32+c][1024 m] bf16 ; xt2[b][m][t*32+c] bf16 --------
// 32-row tiles: LDS 48.1KB -> 3 blocks/CU (was 96KB -> 1 block/CU). grid 1024.
__global__ __launch_bounds__(256) void k0_x(const float* __restrict__ x,
                     unsigned short* __restrict__ xbT, unsigned short* __restrict__ xt2){
  __shared__ unsigned short tile[32*770];        // pad 770: transpose reads conflict-free
  const int b  = blockIdx.x >> 5;
  const int m0 = (blockIdx.x & 31) << 5;
  const int tid = threadIdx.x;
  for (int i = tid; i < 32*192; i += 256){
    int mi = i / 192, c4 = (i - mi*192) << 2;
    f32x4 v = (f32x4){0.f,0.f,0.f,0.f};
    if (m0 + mi < NN) v = *(const f32x4*)(x + (size_t)(b*NN + m0 + mi)*768 + c4);
    unsigned short* tp = tile + mi*770 + c4;
    tp[0] = f2bf(v[0]); tp[1] = f2bf(v[1]); tp[2] = f2bf(v[2]); tp[3] = f2bf(v[3]);
  }
  __syncthreads();
  {
    const int seg = tid & 3, r0 = tid >> 2;      // 4 segs x 8m = 32m; 64 rows/iter
    for (int rr = 0; rr < 768; rr += 64){
      int r = rr + r0;
      int t = r >> 5, c = r & 31, ct = c*24 + t;
      u16x8 v;
      #pragma unroll
      for (int e = 0; e < 8; ++e) v[e] = tile[(seg*8 + e)*770 + ct];
      *(u16x8*)(xbT + ((size_t)b*TCN + r)*NP + m0 + seg*8) = v;
    }
  }
  if (m0 < NN){
    int rows = NN - m0; if (rows > 32) rows = 32;
    for (int i = tid; i < rows*96; i += 256){
      int mi = i / 96, s = i - mi*96;
      u16x8 v;
      #pragma unroll
      for (int e = 0; e < 8; ++e){
        int r = s*8 + e; int t = r >> 5, c = r & 31;
        v[e] = tile[mi*770 + c*24 + t];
      }
      *(u16x8*)(xt2 + (size_t)(b*NN + m0 + mi)*TCN + s*8) = v;
    }
  }
}

// ---------------- K0c: weights -> f-major bf16 ------------------------------------------
__global__ void k0_w(const float* __restrict__ Theta, const float* __restrict__ tw,
                     const float* __restrict__ rw,
                     unsigned short* __restrict__ ThT, unsigned short* __restrict__ WtT,
                     unsigned short* __restrict__ rwT){
  int i = blockIdx.x * 256 + threadIdx.x;
  if (i < 64*96){                       // ThT[f][kc] = Theta[k][c][f]
    int f = i / 96, kc = i - f*96;
    ThT[i] = f2bf(Theta[kc*64 + f]);
  }
  if (i < 64*192){                      // WtT[f][dt*64+fi] = tw[f][fi][0][dt]
    int f = i / 192, kk = i - f*192;
    int dt = kk >> 6, fi = kk & 63;
    WtT[i] = f2bf(tw[(f*64 + fi)*3 + dt]);
  }
  if (i < 64*32){                       // rwT[f][c] = rw[f][c][0][0]
    rwT[i] = f2bf(rw[i]);
  }
}

// ---------------- K1: fused cheb-GEMM (3k) + Theta-GEMM + relu -> spatial ----------------
// (R8-exact, proven 224us / ~690 TF.) 256 threads / 4 waves (2wr x 2wc), block tile
// 64n x 128tc, BK=32, 32x32x16 MFMA, dbuf LDS 40KB + single barrier/step,
// both-sides swizzle s(row) = (row>>1)&3. Structure ceiling confirmed by 5 failed
// restructures (R3/R6/R9/R10/R11/R12) — do not graft partial pipeline techniques.
__global__ __launch_bounds__(256, 3) void k1_cheb_theta(
    const unsigned short* __restrict__ cbT,
    const unsigned short* __restrict__ xbT,
    const unsigned short* __restrict__ ThT,
    unsigned short* __restrict__ spa)
{
  __shared__ __align__(16) unsigned short smem[20480];  // 40KB: 2 x (A[3][64][32] + B[128][32])

  int pB = blockIdx.x;
  int lb = (pB & 7) * 384 + (pB >> 3);     // bijective XCD-chunked swizzle (3072 = 8*384)
  const int tcb = lb % 6; lb /= 6;         // 6 consecutive blocks share the A-panel
  const int nt  = lb & 15;
  const int b   = lb >> 4;

  const int tid  = threadIdx.x;
  const int wid  = tid >> 6;
  const int lane = tid & 63;
  const int l31  = lane & 31;
  const int h    = lane >> 5;
  const int wr   = wid >> 1;    // n-half (32 rows)
  const int wc   = wid & 1;     // tc-half (64 cols)

  const int rl4 = lane >> 2;
  const int swz = (((lane & 3) ^ ((rl4 >> 1) & 3)) << 3);
  const unsigned short* baseA = cbT + (size_t)(nt*64 + rl4)*NP + swz;
  const unsigned short* baseB = xbT + ((size_t)b*TCN + tcb*128 + rl4)*NP + swz;
  char* smc = (char*)smem;

  const int s_rd = (l31 >> 1) & 3;
  const int ch0 = ((h ^ s_rd) << 3);
  const int ch1 = (((2 + h) ^ s_rd) << 3);

  f32x16 acc[3][2];
  #pragma unroll
  for (int k = 0; k < 3; ++k)
    #pragma unroll
    for (int j = 0; j < 2; ++j)
      #pragma unroll
      for (int r = 0; r < 16; ++r) acc[k][j][r] = 0.f;

  const int rA  = wr*32 + l31;     // A-LDS row (n-local)
  const int rB0 = wc*64 + l31;     // B-LDS row (tc-local, j=0)

  // prologue
  {
    #pragma unroll
    for (int q = 0; q < 5; ++q){
      const int g = wid*5 + q;
      if (g < 12){
        const int k = g >> 2, rg = g & 3;
        GLOAD16(baseA + (size_t)k*NP*NP + rg*16*NP, smc + k*4096 + rg*1024);
      } else {
        const int rg = g - 12;
        GLOAD16(baseB + (size_t)rg*16*NP, smc + 12288 + rg*1024);
      }
    }
  }
  __syncthreads();

  int cur = 0;
  for (int step = 0; step < 32; ++step){
    if (step < 31){
      const int so = (step + 1) << 5;
      const int bo = (cur ^ 1) * 20480;
      #pragma unroll
      for (int q = 0; q < 5; ++q){
        const int g = wid*5 + q;
        if (g < 12){
          const int k = g >> 2, rg = g & 3;
          GLOAD16(baseA + (size_t)k*NP*NP + rg*16*NP + so, smc + bo + k*4096 + rg*1024);
        } else {
          const int rg = g - 12;
          GLOAD16(baseB + (size_t)rg*16*NP + so, smc + bo + 12288 + rg*1024);
        }
      }
    }
    const unsigned short* sb = smem + cur*10240;
    #pragma unroll
    for (int ks = 0; ks < 2; ++ks){
      const int ch = ks ? ch1 : ch0;
      s16x8 bf0 = *(const s16x8*)(sb + 6144 + rB0*32 + ch);
      s16x8 bf1 = *(const s16x8*)(sb + 6144 + (rB0 + 32)*32 + ch);
      #pragma unroll
      for (int k = 0; k < 3; ++k){
        s16x8 af = *(const s16x8*)(sb + k*2048 + rA*32 + ch);
        acc[k][0] = __builtin_amdgcn_mfma_f32_32x32x16_bf16(af, bf0, acc[k][0], 0, 0, 0);
        acc[k][1] = __builtin_amdgcn_mfma_f32_32x32x16_bf16(af, bf1, acc[k][1], 0, 0, 0);
      }
    }
    __syncthreads();
    cur ^= 1;
  }

  // ---- epilogue: 4 t-phases; y -> LDS bf16 (chunk-XOR) -> Theta MFMA (32x32) -> relu ----
  s16x8 b2[3][2];
  const int fE = wc*32 + l31;
  #pragma unroll
  for (int ch = 0; ch < 3; ++ch)
    #pragma unroll
    for (int ks = 0; ks < 2; ++ks)
      b2[ch][ks] = *(const s16x8*)(ThT + fE*96 + ch*32 + ks*16 + h*8);

  unsigned short* yl = smem;                 // [64 n][104 kc], chunk-XOR swizzled
  const int rowE = wr*32 + l31;
  #pragma unroll
  for (int p = 0; p < 4; ++p){
    __syncthreads();
    if (wc == (p >> 1)){
      const int jj = p & 1;
      #pragma unroll
      for (int k = 0; k < 3; ++k)
        #pragma unroll
        for (int r = 0; r < 16; ++r){
          const int nl = wr*32 + (r & 3) + ((r >> 2) << 3) + (h << 2);
          const int kc = k*32 + l31;
          const int q  = kc >> 3;
          yl[nl*104 + (((q ^ (nl & 3)) << 3) | (kc & 7))] = f2bf(acc[k][jj][r]);
        }
    }
    __syncthreads();
    f32x16 a2c;
    #pragma unroll
    for (int r = 0; r < 16; ++r) a2c[r] = 0.f;
    #pragma unroll
    for (int ch = 0; ch < 3; ++ch)
      #pragma unroll
      for (int ks = 0; ks < 2; ++ks){
        const int q = ch*4 + ks*2 + h;
        s16x8 a2 = *(const s16x8*)(yl + rowE*104 + ((q ^ (rowE & 3)) << 3));
        a2c = __builtin_amdgcn_mfma_f32_32x32x16_bf16(a2, b2[ch][ks], a2c, 0, 0, 0);
      }
    const int t = tcb*4 + p;
    #pragma unroll
    for (int r = 0; r < 16; ++r){
      const int nl = wr*32 + (r & 3) + ((r >> 2) << 3) + (h << 2);
      const int n  = nt*64 + nl;
      if (n < NN)
        spa[((size_t)(b*NN + n)*NT + t)*64 + fE] = f2bf(fmaxf(a2c[r], 0.f));
    }
  }
}

// ---------------- K2 v4: LDS-staged time-conv + residual + gating -> out f32 ------------
// 2000 blocks x 384 thr (6 waves, 2 x 32-row groups each — shorter tail, 12 waves/CU).
// 16 (b,n) cells/block; spa (48KB) + xt2 (24KB) staged via global_load_lds, both-sides
// XOR swizzle. dt-shift = +/-1 LDS row with clamp+mask; weights from L1.
__global__ __launch_bounds__(384, 3) void k2_out(
    const unsigned short* __restrict__ spa, const unsigned short* __restrict__ xt2,
    const unsigned short* __restrict__ WtT, const unsigned short* __restrict__ rwT,
    const float* __restrict__ tb, const float* __restrict__ rb,
    float* __restrict__ out)
{
  __shared__ __align__(16) unsigned short sst[36864];   // 72KB = spa 48KB + xt2 24KB
  const unsigned short* spa_s = sst;
  const unsigned short* xt2_s = sst + 24576;

  const int c0   = blockIdx.x * 16;
  const int tid  = threadIdx.x;
  const int w    = tid >> 6;
  const int lane = tid & 63;
  const int l31  = lane & 31;
  const int h    = lane >> 5;
  char* smc = (char*)sst;

  // ---- stage: fully coalesced contiguous ranges, source chunk pre-swizzled ----
  const unsigned short* gs = spa + (size_t)c0 * 1536;   // 16 cells x 24t x 64f
  const unsigned short* gx = xt2 + (size_t)c0 * 768;    // 16 cells x 768
  #pragma unroll
  for (int it = 0; it < 8; ++it){                       // spa: rows of 128B, s8(row)=row&7
    const int row = it*48 + (tid >> 3);
    const int sc  = (tid & 7) ^ (row & 7);
    GLOAD16(gs + (size_t)row*64 + sc*8, smc + it*6144 + w*1024);
  }
  #pragma unroll
  for (int it = 0; it < 4; ++it){                       // xt2: rows of 64B, s4=(row>>1)&3
    const int row = it*96 + (tid >> 2);
    const int sc  = (tid & 3) ^ ((row >> 1) & 3);
    GLOAD16(gx + (size_t)row*32 + sc*8, smc + 49152 + it*6144 + w*1024);
  }
  __syncthreads();

  const float tb0v = tb[l31], tb1v = tb[32 + l31];
  const float rb0v = rb[l31], rb1v = rb[32 + l31];

  #pragma unroll
  for (int g = 0; g < 2; ++g){
    const int rbase = w*64 + g*32;
    const int r = rbase + l31;                 // 0..383
    const int cell = r / 24;
    const int t = r - cell*24;

    f32x16 a0, a1, rs0, rs1;
    #pragma unroll
    for (int e = 0; e < 16; ++e){ a0[e]=0.f; a1[e]=0.f; rs0[e]=0.f; rs1[e]=0.f; }

    #pragma unroll
    for (int s = 0; s < 12; ++s){              // time-conv K-slices: dt=s>>2, fb=s&3
      const int dt = s >> 2;
      const int tv = t + dt - 1;
      int ar = r + dt - 1;
      ar = ar < 0 ? 0 : (ar > 383 ? 383 : ar);
      const int cfi = ((s & 3) << 1) + h;
      s16x8 a = *(const s16x8*)(spa_s + (size_t)ar*64 + ((cfi ^ (ar & 7)) << 3));
      if (!((unsigned)tv < 24u)) a = (s16x8){0,0,0,0,0,0,0,0};
      s16x8 b0 = *(const s16x8*)(WtT + (size_t)l31*192 + s*16 + h*8);
      s16x8 b1 = *(const s16x8*)(WtT + (size_t)(32 + l31)*192 + s*16 + h*8);
      a0 = __builtin_amdgcn_mfma_f32_32x32x16_bf16(a, b0, a0, 0, 0, 0);
      a1 = __builtin_amdgcn_mfma_f32_32x32x16_bf16(a, b1, a1, 0, 0, 0);
    }
    #pragma unroll
    for (int s = 0; s < 2; ++s){               // residual K=32
      const int cres = (s << 1) + h;
      s16x8 a = *(const s16x8*)(xt2_s + (size_t)r*32 + ((cres ^ ((r >> 1) & 3)) << 3));
      s16x8 b0 = *(const s16x8*)(rwT + (size_t)l31*32 + s*16 + h*8);
      s16x8 b1 = *(const s16x8*)(rwT + (size_t)(32 + l31)*32 + s*16 + h*8);
      rs0 = __builtin_amdgcn_mfma_f32_32x32x16_bf16(a, b0, rs0, 0, 0, 0);
      rs1 = __builtin_amdgcn_mfma_f32_32x32x16_bf16(a, b1, rs1, 0, 0, 0);
    }

    // gate + store: quad q covers rows rbase + q*8 + 4h + 0..3 (t stays in one cell)
    #pragma unroll
    for (int q = 0; q < 4; ++q){
      const int rq = rbase + q*8 + 4*h;
      const int cq = rq / 24;
      const int tq = rq - cq*24;
      f32x4 v0, v1;
      #pragma unroll
      for (int e = 0; e < 4; ++e){
        float z0 = a0[q*4 + e] + tb0v;
        float e0 = __expf(-z0);
        v0[e] = rs0[q*4 + e] + rb0v + (1.f - e0) * __builtin_amdgcn_rcpf(1.f + e0*e0);
        float z1 = a1[q*4 + e] + tb1v;
        float e1 = __expf(-z1);
        v1[e] = rs1[q*4 + e] + rb1v + (1.f - e1) * __builtin_amdgcn_rcpf(1.f + e1*e1);
      }
      *(f32x4*)(out + ((size_t)(c0 + cq)*64 + l31)*24 + tq)      = v0;
      *(f32x4*)(out + ((size_t)(c0 + cq)*64 + 32 + l31)*24 + tq) = v1;
    }
  }
}

// ---------------- launch -----------------------------------------------------------------
extern "C" void kernel_launch(void* const* d_in, const int* in_sizes, int n_in,
                              void* d_out, int out_size, void* d_ws, size_t ws_size,
                              hipStream_t stream) {
  const float* x     = (const float*)d_in[0];
  const float* cheb  = (const float*)d_in[1];
  const float* Theta = (const float*)d_in[2];
  const float* tw    = (const float*)d_in[3];
  const float* tb    = (const float*)d_in[4];
  const float* rw    = (const float*)d_in[5];
  const float* rb    = (const float*)d_in[6];
  float* out = (float*)d_out;

  char* ws = (char*)d_ws;
  size_t off = 0;
  auto alloc = [&](size_t bytes) -> void* {
    void* p = ws + off;
    off += (bytes + 255) & ~(size_t)255;
    return p;
  };
  unsigned short* cbT = (unsigned short*)alloc((size_t)3*NP*NP*2);        //  6.3 MB
  unsigned short* xbT = (unsigned short*)alloc((size_t)NB*TCN*NP*2);      // 50.3 MB
  unsigned short* xt2 = (unsigned short*)alloc((size_t)NB*NN*TCN*2);      // 49.2 MB
  unsigned short* spa = (unsigned short*)alloc((size_t)NB*NN*NT*64*2);    // 98.3 MB
  unsigned short* ThT = (unsigned short*)alloc((size_t)64*96*2);
  unsigned short* WtT = (unsigned short*)alloc((size_t)64*192*2);
  unsigned short* rwT = (unsigned short*)alloc((size_t)64*32*2);

  hipLaunchKernelGGL(k0_cheb, dim3(3072), dim3(256), 0, stream, cheb, cbT);
  hipLaunchKernelGGL(k0_x,    dim3(1024), dim3(256), 0, stream, x, xbT, xt2);
  hipLaunchKernelGGL(k0_w,    dim3(48),   dim3(256), 0, stream, Theta, tw, rw, ThT, WtT, rwT);
  hipLaunchKernelGGL(k1_cheb_theta, dim3(32*16*6), dim3(256), 0, stream, cbT, xbT, ThT, spa);
  hipLaunchKernelGGL(k2_out,  dim3(2000), dim3(384), 0, stream, spa, xt2, WtT, rwT, tb, rb, out);
}